// Round 3
// baseline (154.986 us; speedup 1.0000x reference)
//
#include <hip/hip_runtime.h>
#include <hip/hip_bf16.h>

// y = x @ W^T + b ; x:(16,8192,256) f32, W:(256,256) f32, b:(256,) f32, out f32
// M=131072, N=256, K=256. Memory-bound (268 MB @ ~6.3 TB/s => ~43 us floor).
// R3: NO LDS, NO BARRIERS. R1/R2 post-mortem: __syncthreads drains vmcnt(0)
//     (compiler-forced), capping latency hiding at one MFMA burst -> 2.2 TB/s.
//     Each wave now reads its A-fragments straight from global (per-lane
//     transposed 32B reads; 4 reqs/128B line merge in L1/MSHR since the ks
//     loop is fully unrolled). W stays in per-wave registers (verified R1).
//     Compiler is free to deep-pipeline loads across ks and tiles.

typedef __attribute__((ext_vector_type(8))) short bf16x8;
typedef __attribute__((ext_vector_type(16))) float f32x16;

__device__ __forceinline__ short f2bf(float f) {
    __hip_bfloat16 h = __float2bfloat16(f);   // RTNE
    return *reinterpret_cast<short*>(&h);
}

#define BM 32

__global__ __launch_bounds__(512, 2)
void rac_linear_kernel(const float* __restrict__ x,
                       const float* __restrict__ w,
                       const float* __restrict__ bias,
                       float* __restrict__ out,
                       int tiles_per_block)
{
    const int tid  = threadIdx.x;
    const int lane = tid & 63;
    const int wv   = tid >> 6;        // 0..7: N-wave, owns cols [wv*32, wv*32+32)
    const int l31  = lane & 31;
    const int lh   = lane >> 5;       // 0/1: k-half of the fragment

    // ---- B prologue: W[n][k] -> per-wave bf16 register fragments ----
    // B frag layout (32x32x16): col = lane&31 (n), k = (lane>>5)*8 + j
    bf16x8 bfrag[16];
    {
        const int   wrow = wv * 32 + l31;                 // n index
        const float* wb  = w + (size_t)wrow * 256 + lh * 8;
        #pragma unroll
        for (int ks = 0; ks < 16; ++ks) {
            const float4 lo = *reinterpret_cast<const float4*>(wb + ks * 16);
            const float4 hi = *reinterpret_cast<const float4*>(wb + ks * 16 + 4);
            bf16x8 b;
            b[0]=f2bf(lo.x); b[1]=f2bf(lo.y); b[2]=f2bf(lo.z); b[3]=f2bf(lo.w);
            b[4]=f2bf(hi.x); b[5]=f2bf(hi.y); b[6]=f2bf(hi.z); b[7]=f2bf(hi.w);
            bfrag[ks] = b;
        }
    }
    const float bval = bias[wv * 32 + l31];

    const int t0 = blockIdx.x * tiles_per_block;

    for (int t = 0; t < tiles_per_block; ++t) {
        const int tile = t0 + t;

        // A-fragments straight from global: lane reads
        //   x[tile*32 + (lane&31)][ks*16 + (lane>>5)*8 + {0..7}]
        const float* xr = x + ((size_t)tile * BM + l31) * 256 + lh * 8;

        f32x16 acc;
        #pragma unroll
        for (int r = 0; r < 16; ++r) acc[r] = bval;

        #pragma unroll
        for (int ks = 0; ks < 16; ++ks) {
            const float4 lo = *reinterpret_cast<const float4*>(xr + ks * 16);
            const float4 hi = *reinterpret_cast<const float4*>(xr + ks * 16 + 4);
            bf16x8 a;
            a[0]=f2bf(lo.x); a[1]=f2bf(lo.y); a[2]=f2bf(lo.z); a[3]=f2bf(lo.w);
            a[4]=f2bf(hi.x); a[5]=f2bf(hi.y); a[6]=f2bf(hi.z); a[7]=f2bf(hi.w);
            acc = __builtin_amdgcn_mfma_f32_32x32x16_bf16(a, bfrag[ks], acc, 0, 0, 0);
        }

        // ---- C layout (verified): col=lane&31, row=(r&3)+8*(r>>2)+4*(lane>>5) ----
        {
            float* ob = out + (size_t)tile * (BM * 256) + wv * 32 + l31;
            const int rhi = lh * 4;
            #pragma unroll
            for (int r = 0; r < 16; ++r) {
                const int row = (r & 3) + 8 * (r >> 2) + rhi;
                ob[(size_t)row * 256] = acc[r];
            }
        }
    }
}

extern "C" void kernel_launch(void* const* d_in, const int* in_sizes, int n_in,
                              void* d_out, int out_size, void* d_ws, size_t ws_size,
                              hipStream_t stream)
{
    const float* x    = (const float*)d_in[0];
    const float* w    = (const float*)d_in[1];
    const float* bias = (const float*)d_in[2];
    float* out        = (float*)d_out;

    const int M      = in_sizes[0] / 256;   // 131072 rows
    const int ntiles = M / BM;              // 4096
    const int grid   = 512;                 // amortize W-prologue (R2 lesson)
    const int tpb    = ntiles / grid;       // 8 tiles per block

    rac_linear_kernel<<<grid, 512, 0, stream>>>(x, w, bias, out, tpb);
}

// Round 4
// 67.671 us; speedup vs baseline: 2.2903x; 2.2903x over previous
//
#include <hip/hip_runtime.h>
#include <hip/hip_bf16.h>

// y = x @ W^T + b ; x:(16,8192,256) f32, W:(256,256) f32, b:(256,) f32, out f32
// M=131072, N=256, K=256. Memory-bound (268 MB @ ~6.3 TB/s => ~43 us floor).
// R4: R1 structure (best, 62us) + barrier-drain fix:
//  - stage LDS at ITER START (consumes loads issued a full iteration ago)
//  - raw s_barrier + lgkmcnt(0) only; stores NEVER drained (no vmcnt(0) in loop)
//  - compiler emits counted vmcnt(16) before the cvt of v (16 stores in flight ok)
// R3 lesson: per-lane transposed global reads = 32 lines/instr = VMEM issue death.

typedef __attribute__((ext_vector_type(8))) short bf16x8;
typedef __attribute__((ext_vector_type(16))) float f32x16;

__device__ __forceinline__ short f2bf(float f) {
    __hip_bfloat16 h = __float2bfloat16(f);   // RTNE
    return *reinterpret_cast<short*>(&h);
}

#define BM   32
#define LDSK 264   // 256+8 pad: 528B row stride -> conflict-free b128 frag reads (measured 0)

__global__ __launch_bounds__(512, 4)
void rac_linear_kernel(const float* __restrict__ x,
                       const float* __restrict__ w,
                       const float* __restrict__ bias,
                       float* __restrict__ out,
                       int tiles_per_block)
{
    __shared__ short lds[2][BM * LDSK];   // 2 x 16.5 KB

    const int tid  = threadIdx.x;
    const int lane = tid & 63;
    const int wv   = tid >> 6;        // 0..7: N-wave, owns cols [wv*32, wv*32+32)
    const int l31  = lane & 31;
    const int lh   = lane >> 5;       // 0/1: k-half of the fragment

    // ---- B prologue: W[n][k] -> per-wave bf16 register fragments ----
    // B frag layout (32x32x16): col = lane&31 (n), k = (lane>>5)*8 + j
    bf16x8 bfrag[16];
    {
        const int   wrow = wv * 32 + l31;                 // n index
        const float* wb  = w + (size_t)wrow * 256 + lh * 8;
        #pragma unroll
        for (int ks = 0; ks < 16; ++ks) {
            const float4 lo = *reinterpret_cast<const float4*>(wb + ks * 16);
            const float4 hi = *reinterpret_cast<const float4*>(wb + ks * 16 + 4);
            bf16x8 b;
            b[0]=f2bf(lo.x); b[1]=f2bf(lo.y); b[2]=f2bf(lo.z); b[3]=f2bf(lo.w);
            b[4]=f2bf(hi.x); b[5]=f2bf(hi.y); b[6]=f2bf(hi.z); b[7]=f2bf(hi.w);
            bfrag[ks] = b;
        }
    }
    const float bval = bias[wv * 32 + l31];

    const int t0  = blockIdx.x * tiles_per_block;
    const int row = (tid >> 6);            // staging row base (wave id)
    const int kk  = (tid & 63) * 4;        // staging k offset

    float4 v[4];   // staging registers (one BM x 256 f32 tile = 64 B/thread)

    // ---- prologue: load+stage tile t0 into buf0; load tile t0+1 into v ----
    {
        const float4* src = reinterpret_cast<const float4*>(x + (size_t)t0 * (BM * 256));
        #pragma unroll
        for (int i = 0; i < 4; ++i) v[i] = src[i * 512 + tid];
        #pragma unroll
        for (int i = 0; i < 4; ++i) {
            short4 s;
            s.x=f2bf(v[i].x); s.y=f2bf(v[i].y); s.z=f2bf(v[i].z); s.w=f2bf(v[i].w);
            *reinterpret_cast<short4*>(&lds[0][(i * 8 + row) * LDSK + kk]) = s;
        }
        const float4* src1 = reinterpret_cast<const float4*>(x + (size_t)(t0 + 1) * (BM * 256));
        #pragma unroll
        for (int i = 0; i < 4; ++i) v[i] = src1[i * 512 + tid];
    }
    __syncthreads();   // one full drain at startup only

    for (int t = 0; t < tiles_per_block; ++t) {
        const int buf  = t & 1;
        const int tile = t0 + t;

        // 1. stage tile t+1 into buf^1 (v = loads issued one full iteration ago;
        //    compiler waits vmcnt(16): stores from last iter may stay in flight)
        if (t + 1 < tiles_per_block) {
            #pragma unroll
            for (int i = 0; i < 4; ++i) {
                short4 s;
                s.x=f2bf(v[i].x); s.y=f2bf(v[i].y); s.z=f2bf(v[i].z); s.w=f2bf(v[i].w);
                *reinterpret_cast<short4*>(&lds[buf ^ 1][(i * 8 + row) * LDSK + kk]) = s;
            }
        }

        // 2. issue loads for tile t+2 (consumed at start of next iteration)
        if (t + 2 < tiles_per_block) {
            const float4* src =
                reinterpret_cast<const float4*>(x + (size_t)(tile + 2) * (BM * 256));
            #pragma unroll
            for (int i = 0; i < 4; ++i) v[i] = src[i * 512 + tid];
        }

        // 3. compute: 16 K-steps of mfma_f32_32x32x16_bf16
        f32x16 acc;
        #pragma unroll
        for (int r = 0; r < 16; ++r) acc[r] = bval;

        const short* abase = &lds[buf][l31 * LDSK + lh * 8];
        #pragma unroll
        for (int ks = 0; ks < 16; ++ks) {
            bf16x8 a = *reinterpret_cast<const bf16x8*>(abase + ks * 16);
            acc = __builtin_amdgcn_mfma_f32_32x32x16_bf16(a, bfrag[ks], acc, 0, 0, 0);
        }

        // 4. epilogue: C layout col=lane&31, row=(r&3)+8*(r>>2)+4*(lane>>5)
        {
            float* ob = out + (size_t)tile * (BM * 256) + wv * 32 + l31;
            const int rhi = lh * 4;
            #pragma unroll
            for (int r = 0; r < 16; ++r) {
                const int rr = (r & 3) + 8 * (r >> 2) + rhi;
                ob[(size_t)rr * 256] = acc[r];
            }
        }

        // 5. LDS-visibility barrier only: lgkmcnt(0) + raw s_barrier.
        //    NO vmcnt drain -- stores and prefetch loads stay in flight.
        if (t + 1 < tiles_per_block)
            asm volatile("s_waitcnt lgkmcnt(0)\n\ts_barrier" ::: "memory");
    }
}

extern "C" void kernel_launch(void* const* d_in, const int* in_sizes, int n_in,
                              void* d_out, int out_size, void* d_ws, size_t ws_size,
                              hipStream_t stream)
{
    const float* x    = (const float*)d_in[0];
    const float* w    = (const float*)d_in[1];
    const float* bias = (const float*)d_in[2];
    float* out        = (float*)d_out;

    const int M      = in_sizes[0] / 256;   // 131072 rows
    const int ntiles = M / BM;              // 4096
    const int grid   = 512;                 // 2 blocks/CU (R1/R2: more blocks hurt)
    const int tpb    = ntiles / grid;       // 8 tiles per block

    rac_linear_kernel<<<grid, 512, 0, stream>>>(x, w, bias, out, tpb);
}

// Round 5
// 58.785 us; speedup vs baseline: 2.6365x; 1.1512x over previous
//
#include <hip/hip_runtime.h>
#include <hip/hip_bf16.h>

// y = x @ W^T + b ; x:(16,8192,256) f32, W:(256,256) f32, b:(256,) f32, out f32
// M=131072, N=256, K=256. Memory-bound.
// R5 = R1 (best, 61.9us) + NONTEMPORAL C-stores.
// Theory: x(134MB) + out(134MB) = 268MB > 256MB L3 -> thrash (FETCH ~70MB/replay).
// out is write-once/no-reuse: nt stores keep it out of L3 -> x becomes fully
// L3-resident across replays; HBM traffic/replay ~134MB writes only.
// R2 lesson: grid>512 hurts (prologue amortization). R3: transposed global
// reads = VMEM issue death. R4: barrier-drain restructure = -6us + write amp.

typedef __attribute__((ext_vector_type(8))) short bf16x8;
typedef __attribute__((ext_vector_type(16))) float f32x16;

__device__ __forceinline__ short f2bf(float f) {
    __hip_bfloat16 h = __float2bfloat16(f);   // RTNE
    return *reinterpret_cast<short*>(&h);
}

#define BM   32
#define LDSK 264   // 256 + 8 pad: keeps 16B row alignment; 528B stride spreads
                   // the 64-lane b128 fragment read evenly over all 32 banks.

__global__ __launch_bounds__(512, 4)
void rac_linear_kernel(const float* __restrict__ x,
                       const float* __restrict__ w,
                       const float* __restrict__ bias,
                       float* __restrict__ out,
                       int tiles_per_block)
{
    __shared__ short lds[2][BM * LDSK];   // 2 x 16.5 KB

    const int tid  = threadIdx.x;
    const int lane = tid & 63;
    const int wv   = tid >> 6;        // 0..7: N-wave, owns cols [wv*32, wv*32+32)
    const int l31  = lane & 31;
    const int lh   = lane >> 5;       // 0/1: k-half of the fragment

    // ---- B prologue: W[n][k] -> per-wave bf16 register fragments ----
    // B frag layout (32x32x16): col = lane&31 (n), k = (lane>>5)*8 + j
    bf16x8 bfrag[16];
    {
        const int   wrow = wv * 32 + l31;                 // n index
        const float* wb  = w + (size_t)wrow * 256 + lh * 8;
        #pragma unroll
        for (int ks = 0; ks < 16; ++ks) {
            const float4 lo = *reinterpret_cast<const float4*>(wb + ks * 16);
            const float4 hi = *reinterpret_cast<const float4*>(wb + ks * 16 + 4);
            bf16x8 b;
            b[0]=f2bf(lo.x); b[1]=f2bf(lo.y); b[2]=f2bf(lo.z); b[3]=f2bf(lo.w);
            b[4]=f2bf(hi.x); b[5]=f2bf(hi.y); b[6]=f2bf(hi.z); b[7]=f2bf(hi.w);
            bfrag[ks] = b;
        }
    }
    const float bval = bias[wv * 32 + l31];

    const int t0 = blockIdx.x * tiles_per_block;

    float4 v[4];   // staging registers (one BM x 256 f32 tile = 64 B/thread)

    // prologue: load + stage tile t0 into buf 0
    {
        const float4* src = reinterpret_cast<const float4*>(x + (size_t)t0 * (BM * 256));
        #pragma unroll
        for (int i = 0; i < 4; ++i) v[i] = src[i * 512 + tid];   // fully coalesced
        #pragma unroll
        for (int i = 0; i < 4; ++i) {
            const int row = i * 8 + (tid >> 6);      // elem = i*2048 + tid*4
            const int k   = (tid & 63) * 4;
            short4 s;
            s.x=f2bf(v[i].x); s.y=f2bf(v[i].y); s.z=f2bf(v[i].z); s.w=f2bf(v[i].w);
            *reinterpret_cast<short4*>(&lds[0][row * LDSK + k]) = s;
        }
    }

    for (int t = 0; t < tiles_per_block; ++t) {
        const int buf  = t & 1;
        const int tile = t0 + t;
        __syncthreads();   // staged buf visible; prev compute on buf^1 done

        // issue next tile's global loads early (latency hidden under compute)
        if (t + 1 < tiles_per_block) {
            const float4* src =
                reinterpret_cast<const float4*>(x + (size_t)(tile + 1) * (BM * 256));
            #pragma unroll
            for (int i = 0; i < 4; ++i) v[i] = src[i * 512 + tid];
        }

        // ---- compute: 16 K-steps of mfma_f32_32x32x16_bf16 ----
        f32x16 acc;
        #pragma unroll
        for (int r = 0; r < 16; ++r) acc[r] = bval;

        // A frag layout: row = lane&31 (m), k = (lane>>5)*8 + j
        const short* abase = &lds[buf][l31 * LDSK + lh * 8];
        #pragma unroll
        for (int ks = 0; ks < 16; ++ks) {
            bf16x8 a = *reinterpret_cast<const bf16x8*>(abase + ks * 16);
            acc = __builtin_amdgcn_mfma_f32_32x32x16_bf16(a, bfrag[ks], acc, 0, 0, 0);
        }

        // ---- epilogue: C layout col=lane&31, row=(r&3)+8*(r>>2)+4*(lane>>5) ----
        // NONTEMPORAL: out has no reuse; keep it out of L3 so x stays resident.
        {
            float* ob = out + (size_t)tile * (BM * 256) + wv * 32 + l31;
            const int rhi = lh * 4;
            #pragma unroll
            for (int r = 0; r < 16; ++r) {
                const int row = (r & 3) + 8 * (r >> 2) + rhi;
                __builtin_nontemporal_store(acc[r], &ob[(size_t)row * 256]);
            }
        }

        // stage next tile into the other buffer (safe: all waves past barrier)
        if (t + 1 < tiles_per_block) {
            #pragma unroll
            for (int i = 0; i < 4; ++i) {
                const int row = i * 8 + (tid >> 6);
                const int k   = (tid & 63) * 4;
                short4 s;
                s.x=f2bf(v[i].x); s.y=f2bf(v[i].y); s.z=f2bf(v[i].z); s.w=f2bf(v[i].w);
                *reinterpret_cast<short4*>(&lds[buf ^ 1][row * LDSK + k]) = s;
            }
        }
    }
}

extern "C" void kernel_launch(void* const* d_in, const int* in_sizes, int n_in,
                              void* d_out, int out_size, void* d_ws, size_t ws_size,
                              hipStream_t stream)
{
    const float* x    = (const float*)d_in[0];
    const float* w    = (const float*)d_in[1];
    const float* bias = (const float*)d_in[2];
    float* out        = (float*)d_out;

    const int M      = in_sizes[0] / 256;   // 131072 rows
    const int ntiles = M / BM;              // 4096
    const int grid   = 512;                 // 2 blocks/CU (R2: more blocks hurt)
    const int tpb    = ntiles / grid;       // 8 tiles per block

    rac_linear_kernel<<<grid, 512, 0, stream>>>(x, w, bias, out, tpb);
}